// Round 10
// baseline (117.441 us; speedup 1.0000x reference)
//
#include <hip/hip_runtime.h>

// Fused iterated 3x3 median blur (edge-replicate), up to 9 iterations.
//
// R10: WAVE-SHUFFLE ring exchange — the k-loop has ZERO LDS ops and ZERO
// barriers. Diagnosis history: all ring/LDS variants (R3-R9) pinned at
// 44-62us by the shared per-CU DS unit (R5: 8.2M conflict-cycles = 13us/CU
// + ~14k cy base traffic + per-iter barrier drains). Patch perimeters are
// exchanged with __shfl (wave-synchronous, conflict-free, barrier-free):
//   up/down rows: __shfl_up/down(row5/row0, 8); left/right cols:
//   __shfl_up/down(col5/col0, 1); corners: deltas 7/9.
// Tile-boundary lanes consume the STATIC state-0 halo, preloaded once into
// registers (outer ring was never updated in R5 either; validity absorbs).
//
// Geometry/fixups = R5 (VERIFIED absmax 0): one wave per block, 32x32
// output tile, 50x50 LDS halo (RAD=9), lane (pty=tid>>3, ptx=tid&7) owns a
// 6x6 patch of region [1,48]^2; stage updated in place (old row in B-roll,
// next row read into C first). Validity [k,49-k], k<=9 -> [9,40]^2 =
// output. Image-edge replicate pads = register fixups in pad-owning lanes
// (row fix then col fix -> corners exact); neighbors see post-fixup regs
// via next iteration's shuffles. MEDSTEP = R6 (VERIFIED).
// LDS touched only at: halo load, final publish, store.

#define TD  50
#define OW  32
#define RAD 9
#define NT  64

static __device__ __forceinline__ float min3f(float a, float b, float c) { return fminf(fminf(a, b), c); }
static __device__ __forceinline__ float max3f(float a, float b, float c) { return fmaxf(fmaxf(a, b), c); }
static __device__ __forceinline__ float med3f(float a, float b, float c) { return __builtin_amdgcn_fmed3f(a, b, c); }

// median-of-9 over 8-wide window rows A,B,C -> 6 outputs; rolls A<-B<-C.
#define MEDSTEP(O0,O1,O2,O3,O4,O5) { \
    float lo0=min3f(A0,B0,C0), mi0=med3f(A0,B0,C0), hi0=max3f(A0,B0,C0); \
    float lo1=min3f(A1,B1,C1), mi1=med3f(A1,B1,C1), hi1=max3f(A1,B1,C1); \
    float lo2=min3f(A2,B2,C2), mi2=med3f(A2,B2,C2), hi2=max3f(A2,B2,C2); \
    float lo3=min3f(A3,B3,C3), mi3=med3f(A3,B3,C3), hi3=max3f(A3,B3,C3); \
    float lo4=min3f(A4,B4,C4), mi4=med3f(A4,B4,C4), hi4=max3f(A4,B4,C4); \
    float lo5=min3f(A5,B5,C5), mi5=med3f(A5,B5,C5), hi5=max3f(A5,B5,C5); \
    float lo6=min3f(A6,B6,C6), mi6=med3f(A6,B6,C6), hi6=max3f(A6,B6,C6); \
    float lo7=min3f(A7,B7,C7), mi7=med3f(A7,B7,C7), hi7=max3f(A7,B7,C7); \
    O0 = med3f(max3f(lo0,lo1,lo2), med3f(mi0,mi1,mi2), min3f(hi0,hi1,hi2)); \
    O1 = med3f(max3f(lo1,lo2,lo3), med3f(mi1,mi2,mi3), min3f(hi1,hi2,hi3)); \
    O2 = med3f(max3f(lo2,lo3,lo4), med3f(mi2,mi3,mi4), min3f(hi2,hi3,hi4)); \
    O3 = med3f(max3f(lo3,lo4,lo5), med3f(mi3,mi4,mi5), min3f(hi3,hi4,hi5)); \
    O4 = med3f(max3f(lo4,lo5,lo6), med3f(mi4,mi5,mi6), min3f(hi4,hi5,hi6)); \
    O5 = med3f(max3f(lo5,lo6,lo7), med3f(mi5,mi6,mi7), min3f(hi5,hi6,hi7)); \
    A0=B0;A1=B1;A2=B2;A3=B3;A4=B4;A5=B5;A6=B6;A7=B7; \
    B0=C0;B1=C1;B2=C2;B3=C3;B4=C4;B5=C5;B6=C6;B7=C7; }

__global__ __launch_bounds__(NT) void median_fused_kernel(
    const float* __restrict__ src, float* __restrict__ dst,
    const int* __restrict__ t)
{
    __shared__ float buf[TD * TD];    // 10 KB

    const int b   = blockIdx.y;
    const int ty  = blockIdx.x >> 4;
    const int tx  = blockIdx.x & 15;
    const int y0  = ty * OW;
    const int x0  = tx * OW;
    const int tid = threadIdx.x;
    const float* img  = src + (b << 18);
    float*       outb = dst + (b << 18);

    int T = t[b];
    T = min(max(T, 0), 9);

    if (T == 0) {                       // straight vector copy, no LDS
        for (int idx = tid; idx < 256; idx += NT) {   // 32 rows x 8 float4
            int row = idx >> 3, c4 = idx & 7;
            *(float4*)&outb[((y0 + row) << 9) + x0 + (c4 << 2)] =
                *(const float4*)&img[((y0 + row) << 9) + x0 + (c4 << 2)];
        }
        return;
    }

    // ---- load 50x50 halo tile, clamped (= replicate-padded image) ----
    for (int i = tid; i < TD * TD; i += NT) {
        int r = i / TD, c = i - r * TD;
        int gy = min(max(y0 - RAD + r, 0), 511);
        int gx = min(max(x0 - RAD + c, 0), 511);
        buf[i] = img[(gy << 9) + gx];
    }

    const int ptx = tid & 7;            // 8 col groups x 6
    const int pty = tid >> 3;           // 8 row groups x 6
    const int ub  = 1 + 6 * pty;        // patch rows [ub, ub+5]
    const int vb  = 1 + 6 * ptx;        // patch cols [vb, vb+5]

    const bool topB = (pty == 0), botB = (pty == 7);
    const bool lftB = (ptx == 0), rgtB = (ptx == 7);

    // image-edge pad-owning lanes (R5-verified indices)
    const bool padTop = (y0 == 0)   && (pty == 1);
    const bool padBot = (y0 == 480) && (pty == 6);
    const bool padLft = (x0 == 0)   && (ptx == 1);
    const bool padRgt = (x0 == 480) && (ptx == 6);

    __syncthreads();                    // halo tile ready (only barrier pre-loop)

    // ---- static outer-halo registers for tile-boundary lanes (state 0,
    //      never updated; identical semantics to R5's never-written ring) ----
    float topA[8], botC[8], lftL[8], rgtR[8];
    #pragma unroll
    for (int j = 0; j < 8; ++j) topA[j] = topB ? buf[0 * TD + (vb - 1 + j)] : 0.f;
    #pragma unroll
    for (int j = 0; j < 8; ++j) botC[j] = botB ? buf[49 * TD + (vb - 1 + j)] : 0.f;
    #pragma unroll
    for (int i = 0; i < 8; ++i) lftL[i] = lftB ? buf[(ub - 1 + i) * TD + 0] : 0.f;
    #pragma unroll
    for (int i = 0; i < 8; ++i) rgtR[i] = rgtB ? buf[(ub - 1 + i) * TD + 49] : 0.f;

    // ---- preload own 6x6 patch (state 0) ----
    float stage[36];
    #pragma unroll
    for (int i = 0; i < 6; ++i)
        #pragma unroll
        for (int j = 0; j < 6; ++j)
            stage[i * 6 + j] = buf[(ub + i) * TD + vb + j];

    for (int k = 0; k < T; ++k) {
        // ---- gather all externals at state k via wave shuffles ----
        float a1 = __shfl_up(stage[30], 8), a2 = __shfl_up(stage[31], 8);
        float a3 = __shfl_up(stage[32], 8), a4 = __shfl_up(stage[33], 8);
        float a5 = __shfl_up(stage[34], 8), a6 = __shfl_up(stage[35], 8);
        float aul = __shfl_up(stage[35], 9);            // up-left corner
        float aur = __shfl_up(stage[30], 7);            // up-right corner
        float d1 = __shfl_down(stage[0], 8), d2 = __shfl_down(stage[1], 8);
        float d3 = __shfl_down(stage[2], 8), d4 = __shfl_down(stage[3], 8);
        float d5 = __shfl_down(stage[4], 8), d6 = __shfl_down(stage[5], 8);
        float ddl = __shfl_down(stage[5], 7);           // down-left corner
        float ddr = __shfl_down(stage[0], 9);           // down-right corner
        float l0 = __shfl_up(stage[5], 1),  l1 = __shfl_up(stage[11], 1);
        float l2 = __shfl_up(stage[17], 1), l3 = __shfl_up(stage[23], 1);
        float l4 = __shfl_up(stage[29], 1), l5 = __shfl_up(stage[35], 1);
        float r0 = __shfl_down(stage[0], 1),  r1 = __shfl_down(stage[6], 1);
        float r2 = __shfl_down(stage[12], 1), r3 = __shfl_down(stage[18], 1);
        float r4 = __shfl_down(stage[24], 1), r5 = __shfl_down(stage[30], 1);

        // boundary overrides (static halo)
        float A0 = topB ? topA[0] : (lftB ? lftL[0] : aul);
        float A1 = topB ? topA[1] : a1;
        float A2 = topB ? topA[2] : a2;
        float A3 = topB ? topA[3] : a3;
        float A4 = topB ? topA[4] : a4;
        float A5 = topB ? topA[5] : a5;
        float A6 = topB ? topA[6] : a6;
        float A7 = topB ? topA[7] : (rgtB ? rgtR[0] : aur);

        float Dn0 = botB ? botC[0] : (lftB ? lftL[7] : ddl);
        float Dn1 = botB ? botC[1] : d1;
        float Dn2 = botB ? botC[2] : d2;
        float Dn3 = botB ? botC[3] : d3;
        float Dn4 = botB ? botC[4] : d4;
        float Dn5 = botB ? botC[5] : d5;
        float Dn6 = botB ? botC[6] : d6;
        float Dn7 = botB ? botC[7] : (rgtB ? rgtR[7] : ddr);

        float Lc0 = lftB ? lftL[1] : l0, Lc1 = lftB ? lftL[2] : l1;
        float Lc2 = lftB ? lftL[3] : l2, Lc3 = lftB ? lftL[4] : l3;
        float Lc4 = lftB ? lftL[5] : l4, Lc5 = lftB ? lftL[6] : l5;
        float Rc0 = rgtB ? rgtR[1] : r0, Rc1 = rgtB ? rgtR[2] : r1;
        float Rc2 = rgtB ? rgtR[3] : r2, Rc3 = rgtB ? rgtR[4] : r3;
        float Rc4 = rgtB ? rgtR[5] : r4, Rc5 = rgtB ? rgtR[6] : r5;

        // ---- 6 in-place MEDSTEPs (R5-proven hazard order) ----
        float B0 = Lc0, B1 = stage[0], B2 = stage[1], B3 = stage[2],
              B4 = stage[3], B5 = stage[4], B6 = stage[5], B7 = Rc0;
        float C0, C1, C2, C3, C4, C5, C6, C7;

        C0=Lc1; C1=stage[6];  C2=stage[7];  C3=stage[8];  C4=stage[9];  C5=stage[10]; C6=stage[11]; C7=Rc1;
        MEDSTEP(stage[0],stage[1],stage[2],stage[3],stage[4],stage[5])
        C0=Lc2; C1=stage[12]; C2=stage[13]; C3=stage[14]; C4=stage[15]; C5=stage[16]; C6=stage[17]; C7=Rc2;
        MEDSTEP(stage[6],stage[7],stage[8],stage[9],stage[10],stage[11])
        C0=Lc3; C1=stage[18]; C2=stage[19]; C3=stage[20]; C4=stage[21]; C5=stage[22]; C6=stage[23]; C7=Rc3;
        MEDSTEP(stage[12],stage[13],stage[14],stage[15],stage[16],stage[17])
        C0=Lc4; C1=stage[24]; C2=stage[25]; C3=stage[26]; C4=stage[27]; C5=stage[28]; C6=stage[29]; C7=Rc4;
        MEDSTEP(stage[18],stage[19],stage[20],stage[21],stage[22],stage[23])
        C0=Lc5; C1=stage[30]; C2=stage[31]; C3=stage[32]; C4=stage[33]; C5=stage[34]; C6=stage[35]; C7=Rc5;
        MEDSTEP(stage[24],stage[25],stage[26],stage[27],stage[28],stage[29])
        C0=Dn0; C1=Dn1; C2=Dn2; C3=Dn3; C4=Dn4; C5=Dn5; C6=Dn6; C7=Dn7;
        MEDSTEP(stage[30],stage[31],stage[32],stage[33],stage[34],stage[35])

        // ---- image-edge pad fixups (R5-verified; neighbors see post-fixup
        //      values via next iteration's shuffles) ----
        if (padTop) {                   // row i=1 (r=9-1) <- row i=2
            #pragma unroll
            for (int j = 0; j < 6; ++j) stage[6 + j] = stage[12 + j];
        }
        if (padBot) {                   // row i=4 <- row i=3
            #pragma unroll
            for (int j = 0; j < 6; ++j) stage[24 + j] = stage[18 + j];
        }
        if (padLft) {                   // col j=1 <- col j=2
            #pragma unroll
            for (int i = 0; i < 6; ++i) stage[i * 6 + 1] = stage[i * 6 + 2];
        }
        if (padRgt) {                   // col j=4 <- col j=3
            #pragma unroll
            for (int i = 0; i < 6; ++i) stage[i * 6 + 4] = stage[i * 6 + 3];
        }
        // no barriers, no LDS: next iteration's shuffles read these regs
    }

    // ---- publish all 36 cells once, then store ----
    #pragma unroll
    for (int i = 0; i < 6; ++i)
        #pragma unroll
        for (int j = 0; j < 6; ++j)
            buf[(ub + i) * TD + vb + j] = stage[i * 6 + j];
    __syncthreads();

    // ---- store 32x32 output tile (tile rows/cols 9..40), float4 global ----
    for (int idx = tid; idx < 256; idx += NT) {       // 32 rows x 8 float4
        int row = idx >> 3, c4 = idx & 7;
        const float* s = &buf[(RAD + row) * TD + RAD + (c4 << 2)];
        float4 v = { s[0], s[1], s[2], s[3] };
        *(float4*)&outb[((y0 + row) << 9) + x0 + (c4 << 2)] = v;
    }
}

extern "C" void kernel_launch(void* const* d_in, const int* in_sizes, int n_in,
                              void* d_out, int out_size, void* d_ws, size_t ws_size,
                              hipStream_t stream) {
    const float* x   = (const float*)d_in[0];
    const int*   t   = (const int*)d_in[1];
    float*       out = (float*)d_out;

    dim3 block(NT);
    dim3 grid(256, 32);   // 16x16 tiles of 32 x 32 batches
    median_fused_kernel<<<grid, block, 0, stream>>>(x, out, t);
}